// Round 7
// baseline (448.134 us; speedup 1.0000x reference)
//
#include <hip/hip_runtime.h>
#include <hip/hip_bf16.h>
#include <math.h>

#define N_NODES 8192
#define IN_F    512
#define OUT_F   256
#define NCAT    512
#define ALPHA   0.2f
#define MAXDEG  512          // scan LDS capacity (deg ~ 64 +/- 8)
#define LSTRIDE 256          // list row stride; P(deg>256) ~ 0 (24 sigma)

typedef __attribute__((ext_vector_type(8))) short short8;
typedef __attribute__((ext_vector_type(4))) short short4e;
typedef __attribute__((ext_vector_type(4))) float f32x4;
typedef __attribute__((ext_vector_type(2))) int  i32x2;

static __device__ __forceinline__ short f2bf(float f) {
    union { float f; unsigned u; } v; v.f = f;
    unsigned r = v.u + 0x7fffu + ((v.u >> 16) & 1u);   // RNE
    return (short)(r >> 16);
}
static __device__ __forceinline__ float bf2f(short s) {
    union { unsigned u; float f; } v;
    v.u = ((unsigned)(unsigned short)s) << 16;
    return v.f;
}

// ---------------------------------------------------------------------------
// Prepack B^T bf16: Bt[n][k]; n<256 -> W[:,n], n>=256 -> W_gc[:,n-256]
// ---------------------------------------------------------------------------
__global__ __launch_bounds__(512) void bt_pack(const float* __restrict__ W,
                                               const float* __restrict__ W_gc,
                                               short* __restrict__ Bt) {
    const int n = blockIdx.x;
    const int k = threadIdx.x;
    float v = (n < OUT_F) ? W[(size_t)k * OUT_F + n]
                          : W_gc[(size_t)k * OUT_F + (n - OUT_F)];
    Bt[(size_t)n * IN_F + k] = f2bf(v);
}

// ---------------------------------------------------------------------------
// MFMA bf16 GEMM: [h_t | g_t] = bf16(inputs) @ Bt^T ; 128x128 tile/block.
// ---------------------------------------------------------------------------
__global__ __launch_bounds__(256) void gemm_mfma(const float* __restrict__ A,
                                                 const short* __restrict__ Bt,
                                                 short* __restrict__ h_t,
                                                 short* __restrict__ g_t) {
    __shared__ short As[128 * 32];
    __shared__ short Bs[128 * 32];

    const int tid  = threadIdx.x;
    const int m0   = blockIdx.y * 128;
    const int n0   = blockIdx.x * 128;
    const int wid  = tid >> 6;
    const int lane = tid & 63;
    const int wr   = wid >> 1;
    const int wc   = wid & 1;
    const int mh   = lane & 15;
    const int q    = lane >> 4;

    const int srow  = tid >> 1;
    const int shalf = tid & 1;

    const f32x4 vzero = {0.f, 0.f, 0.f, 0.f};
    f32x4 acc[4][4];
    #pragma unroll
    for (int i = 0; i < 4; i++)
        #pragma unroll
        for (int j = 0; j < 4; j++) acc[i][j] = vzero;

    const float* aga = A  + (size_t)(m0 + srow) * IN_F + shalf * 16;
    const short* bgb = Bt + (size_t)(n0 + srow) * IN_F + shalf * 16;
    short* asw = &As[srow * 32 + shalf * 16];
    short* bsw = &Bs[srow * 32 + shalf * 16];

    for (int k0 = 0; k0 < IN_F; k0 += 32) {
        const float4* a4 = (const float4*)(aga + k0);
        float4 x0 = a4[0], x1 = a4[1], x2 = a4[2], x3 = a4[3];
        const int4* b4 = (const int4*)(bgb + k0);
        int4 bv0 = b4[0], bv1 = b4[1];

        short8 p0, p1;
        p0[0] = f2bf(x0.x); p0[1] = f2bf(x0.y); p0[2] = f2bf(x0.z); p0[3] = f2bf(x0.w);
        p0[4] = f2bf(x1.x); p0[5] = f2bf(x1.y); p0[6] = f2bf(x1.z); p0[7] = f2bf(x1.w);
        p1[0] = f2bf(x2.x); p1[1] = f2bf(x2.y); p1[2] = f2bf(x2.z); p1[3] = f2bf(x2.w);
        p1[4] = f2bf(x3.x); p1[5] = f2bf(x3.y); p1[6] = f2bf(x3.z); p1[7] = f2bf(x3.w);

        __syncthreads();
        *(short8*)asw       = p0;
        *(short8*)(asw + 8) = p1;
        *(int4*)bsw         = bv0;
        *(int4*)(bsw + 8)   = bv1;
        __syncthreads();

        short8 af[4], bfm[4];
        #pragma unroll
        for (int i = 0; i < 4; i++) {
            af[i]  = *(const short8*)&As[(wr * 64 + i * 16 + mh) * 32 + q * 8];
            bfm[i] = *(const short8*)&Bs[(wc * 64 + i * 16 + mh) * 32 + q * 8];
        }
        #pragma unroll
        for (int mi = 0; mi < 4; mi++)
            #pragma unroll
            for (int ni = 0; ni < 4; ni++)
                acc[mi][ni] = __builtin_amdgcn_mfma_f32_16x16x32_bf16(
                    af[mi], bfm[ni], acc[mi][ni], 0, 0, 0);
    }

    short* tab  = (n0 < OUT_F) ? h_t : g_t;
    const int cb = (n0 < OUT_F) ? n0 : n0 - OUT_F;
    #pragma unroll
    for (int mi = 0; mi < 4; mi++)
        #pragma unroll
        for (int ni = 0; ni < 4; ni++) {
            const int col   = cb + wc * 64 + ni * 16 + mh;
            const int rbase = m0 + wr * 64 + mi * 16 + q * 4;
            f32x4 v = acc[mi][ni];
            #pragma unroll
            for (int r = 0; r < 4; r++)
                tab[(size_t)(rbase + r) * OUT_F + col] = f2bf(v[r]);
        }
}

// ---------------------------------------------------------------------------
// f_src[i] = h[i,:].a[0:256], f_dst[i] = h[i,:].a[256:512]
// ---------------------------------------------------------------------------
__global__ __launch_bounds__(256) void compute_f(const short* __restrict__ h_t,
                                                 const float* __restrict__ a,
                                                 float* __restrict__ f_src,
                                                 float* __restrict__ f_dst) {
    const int row  = blockIdx.x * 4 + (threadIdx.x >> 6);
    const int lane = threadIdx.x & 63;
    const int c0   = lane * 4;
    short4e v = *(const short4e*)(h_t + (size_t)row * OUT_F + c0);
    float s1 = 0.f, s2 = 0.f;
    #pragma unroll
    for (int i = 0; i < 4; i++) {
        float hv = bf2f(v[i]);
        s1 += hv * a[c0 + i];
        s2 += hv * a[OUT_F + c0 + i];
    }
    #pragma unroll
    for (int off = 32; off; off >>= 1) {
        s1 += __shfl_down(s1, off);
        s2 += __shfl_down(s2, off);
    }
    if (lane == 0) { f_src[row] = s1; f_dst[row] = s2; }
}

// ---------------------------------------------------------------------------
// Scan: register-prefetch the full 32 KB adj row (8 x f32x4 / thread), then
// compact (idx, w=exp(lrelu(fs+fd))) into LDS; write list + cnt + lsum.
// No max-subtraction (|fs+fd| <~ 20 -> exp fits fp32; validated R5/R6).
// ---------------------------------------------------------------------------
__global__ __launch_bounds__(256) void attn_scan(const float* __restrict__ adj,
                                                 const float* __restrict__ f_src,
                                                 const float* __restrict__ f_dst,
                                                 i32x2* __restrict__ list,
                                                 int* __restrict__ cnt,
                                                 float* __restrict__ lsum) {
    __shared__ int   s_idx[MAXDEG];
    __shared__ float s_w[MAXDEG];
    __shared__ float s_red[4];
    __shared__ int   s_count;

    const int row  = blockIdx.x;
    const int tid  = threadIdx.x;
    const int lane = tid & 63;
    const int wid  = tid >> 6;

    if (tid == 0) s_count = 0;
    __syncthreads();

    const float fs = f_src[row];
    const f32x4* arow4 = (const f32x4*)(adj + (size_t)row * N_NODES);

    f32x4 v[8];
    #pragma unroll
    for (int it = 0; it < 8; it++)
        v[it] = arow4[it * 256 + tid];

    float lloc = 0.f;
    #pragma unroll
    for (int it = 0; it < 8; it++) {
        int c4 = (v[it][0] > 0.f) + (v[it][1] > 0.f) +
                 (v[it][2] > 0.f) + (v[it][3] > 0.f);
        if (c4) {
            int pos = atomicAdd(&s_count, c4);
            const int j0 = (it * 256 + tid) * 4;
            #pragma unroll
            for (int i = 0; i < 4; i++) {
                if (v[it][i] > 0.f) {
                    float e = fs + f_dst[j0 + i];
                    e = (e > 0.f) ? e : ALPHA * e;
                    float w = __expf(e);
                    s_idx[pos] = j0 + i;
                    s_w[pos]   = w;
                    pos++;
                    lloc += w;
                }
            }
        }
    }
    #pragma unroll
    for (int off = 32; off; off >>= 1) lloc += __shfl_down(lloc, off);
    if (lane == 0) s_red[wid] = lloc;
    __syncthreads();

    const int deg = min(s_count, LSTRIDE);
    i32x2* lrow = list + (size_t)row * LSTRIDE;
    for (int k = tid; k < deg; k += 256) {
        i32x2 e; e[0] = s_idx[k]; e[1] = __float_as_int(s_w[k]);
        __builtin_nontemporal_store(e, lrow + k);
    }
    if (tid == 0) {
        cnt[row]  = deg;
        lsum[row] = s_red[0] + s_red[1] + s_red[2] + s_red[3];
    }
}

// ---------------------------------------------------------------------------
// gather_h: ONLY touches the 4 MB h_t table (fits one XCD L2) + NT streams.
// hpart[row][c] = (sum_j w_j * h_t[j][c]) / l.
// lane = 32*sub + p: sub in {0,1} neighbor-subgroup, p covers cols 8p..8p+7.
// ---------------------------------------------------------------------------
__global__ __launch_bounds__(256) void gather_h(const short* __restrict__ h_t,
                                                const i32x2* __restrict__ list,
                                                const int* __restrict__ cnt,
                                                const float* __restrict__ lsum,
                                                float* __restrict__ hpart) {
    __shared__ int   s_idx[LSTRIDE];
    __shared__ float s_w[LSTRIDE];
    __shared__ float s_part[4][32][9];

    const int row  = blockIdx.x;
    const int tid  = threadIdx.x;
    const int lane = tid & 63;
    const int wid  = tid >> 6;

    const int   deg   = cnt[row];
    const float inv_l = (deg > 0) ? 1.f / lsum[row] : 0.f;

    const i32x2* lrow = list + (size_t)row * LSTRIDE;
    for (int k = tid; k < deg; k += 256) {
        i32x2 e = __builtin_nontemporal_load(lrow + k);
        s_idx[k] = e[0];
        s_w[k]   = __int_as_float(e[1]);
    }
    __syncthreads();

    const int sub = lane >> 5;
    const int p   = lane & 31;
    const int nb0 = wid * 2 + sub;
    const short* hb = h_t + p * 8;

    float acc[8] = {0.f, 0.f, 0.f, 0.f, 0.f, 0.f, 0.f, 0.f};
    #pragma unroll 4
    for (int k = nb0; k < deg; k += 8) {
        const int   j = s_idx[k];
        const float w = s_w[k];
        short8 v = *(const short8*)(hb + (size_t)j * OUT_F);
        #pragma unroll
        for (int i = 0; i < 8; i++) acc[i] += w * bf2f(v[i]);
    }
    #pragma unroll
    for (int i = 0; i < 8; i++) acc[i] += __shfl_down(acc[i], 32);
    if (sub == 0) {
        #pragma unroll
        for (int i = 0; i < 8; i++) s_part[wid][p][i] = acc[i];
    }
    __syncthreads();
    const int pc = tid >> 3, ic = tid & 7;
    float hs = (s_part[0][pc][ic] + s_part[1][pc][ic]
              + s_part[2][pc][ic] + s_part[3][pc][ic]) * inv_l;
    __builtin_nontemporal_store(hs, hpart + (size_t)row * OUT_F + tid);
}

// ---------------------------------------------------------------------------
// gather_g: ONLY touches the 4 MB g_t table (fits one XCD L2) + NT streams.
// out[row][c] = hpart[row][c] + sum_j g_t[j][c] + b_gc[c].
// ---------------------------------------------------------------------------
__global__ __launch_bounds__(256) void gather_g(const short* __restrict__ g_t,
                                                const i32x2* __restrict__ list,
                                                const int* __restrict__ cnt,
                                                const float* __restrict__ hpart,
                                                const float* __restrict__ b_gc,
                                                float* __restrict__ out) {
    __shared__ int   s_idx[LSTRIDE];
    __shared__ float s_part[4][32][9];

    const int row  = blockIdx.x;
    const int tid  = threadIdx.x;
    const int lane = tid & 63;
    const int wid  = tid >> 6;

    const int deg = cnt[row];

    const i32x2* lrow = list + (size_t)row * LSTRIDE;
    for (int k = tid; k < deg; k += 256) {
        i32x2 e = __builtin_nontemporal_load(lrow + k);
        s_idx[k] = e[0];
    }
    __syncthreads();

    const int sub = lane >> 5;
    const int p   = lane & 31;
    const int nb0 = wid * 2 + sub;
    const short* gb = g_t + p * 8;

    float acc[8] = {0.f, 0.f, 0.f, 0.f, 0.f, 0.f, 0.f, 0.f};
    #pragma unroll 4
    for (int k = nb0; k < deg; k += 8) {
        const int j = s_idx[k];
        short8 v = *(const short8*)(gb + (size_t)j * OUT_F);
        #pragma unroll
        for (int i = 0; i < 8; i++) acc[i] += bf2f(v[i]);
    }
    #pragma unroll
    for (int i = 0; i < 8; i++) acc[i] += __shfl_down(acc[i], 32);
    if (sub == 0) {
        #pragma unroll
        for (int i = 0; i < 8; i++) s_part[wid][p][i] = acc[i];
    }
    __syncthreads();
    const int pc = tid >> 3, ic = tid & 7;
    float gs = s_part[0][pc][ic] + s_part[1][pc][ic]
             + s_part[2][pc][ic] + s_part[3][pc][ic];
    float hp = __builtin_nontemporal_load(hpart + (size_t)row * OUT_F + tid);
    float o  = hp + gs + b_gc[tid];
    __builtin_nontemporal_store(o, out + (size_t)row * OUT_F + tid);
}

// ---------------------------------------------------------------------------
extern "C" void kernel_launch(void* const* d_in, const int* in_sizes, int n_in,
                              void* d_out, int out_size, void* d_ws, size_t ws_size,
                              hipStream_t stream) {
    const float* inputs = (const float*)d_in[0];   // [8192,512]
    const float* adj    = (const float*)d_in[1];   // [8192,8192]
    const float* W      = (const float*)d_in[2];   // [512,256]
    const float* a      = (const float*)d_in[3];   // [512,1]
    const float* W_gc   = (const float*)d_in[4];   // [512,256]
    const float* b_gc   = (const float*)d_in[5];   // [256]
    float* out = (float*)d_out;                    // [8192,256]

    short* Bt    = (short*)d_ws;                             // 0.5 MB
    short* h_t   = Bt + (size_t)NCAT * IN_F;                 // 4 MB
    short* g_t   = h_t + (size_t)N_NODES * OUT_F;            // 4 MB
    float* f_src = (float*)(g_t + (size_t)N_NODES * OUT_F);  // 32 KB
    float* f_dst = f_src + N_NODES;                          // 32 KB
    float* lsum  = f_dst + N_NODES;                          // 32 KB
    int*   cnt   = (int*)(lsum + N_NODES);                   // 32 KB
    float* hpart = (float*)(cnt + N_NODES);                  // 8 MB
    i32x2* list  = (i32x2*)(hpart + (size_t)N_NODES * OUT_F);// 16 MB
    // total ~33 MB

    bt_pack<<<dim3(NCAT), dim3(IN_F), 0, stream>>>(W, W_gc, Bt);
    gemm_mfma<<<dim3(NCAT / 128, N_NODES / 128), 256, 0, stream>>>(inputs, Bt, h_t, g_t);
    compute_f<<<N_NODES / 4, 256, 0, stream>>>(h_t, a, f_src, f_dst);
    attn_scan<<<N_NODES, 256, 0, stream>>>(adj, f_src, f_dst, list, cnt, lsum);
    gather_h<<<N_NODES, 256, 0, stream>>>(h_t, list, cnt, lsum, hpart);
    gather_g<<<N_NODES, 256, 0, stream>>>(g_t, list, cnt, hpart, b_gc, out);
}

// Round 8
// 434.819 us; speedup vs baseline: 1.0306x; 1.0306x over previous
//
#include <hip/hip_runtime.h>
#include <hip/hip_bf16.h>
#include <math.h>

#define N_NODES 8192
#define IN_F    512
#define OUT_F   256
#define NCAT    512
#define ALPHA   0.2f
#define MAXDEG  512          // deg ~ Binomial(8192,1/128): mean 64, sd 8
#define RSTRIDE 768          // node record: 256 B fp8 h | 512 B bf16 g

typedef __attribute__((ext_vector_type(8))) short short8;
typedef __attribute__((ext_vector_type(4))) short short4e;
typedef __attribute__((ext_vector_type(4))) float f32x4;

static __device__ __forceinline__ short f2bf(float f) {
    union { float f; unsigned u; } v; v.f = f;
    unsigned r = v.u + 0x7fffu + ((v.u >> 16) & 1u);   // RNE
    return (short)(r >> 16);
}
static __device__ __forceinline__ float bf2f(short s) {
    union { unsigned u; float f; } v;
    v.u = ((unsigned)(unsigned short)s) << 16;
    return v.f;
}

// fp8 e4m3fn encode (cold path: GEMM epilogue only). RNE, clamp 448, denorms.
static __device__ __forceinline__ unsigned char f2fp8(float f) {
    union { float f; unsigned u; } v; v.f = f;
    unsigned s = (v.u >> 24) & 0x80u;
    float af = fabsf(f);
    if (af >= 448.f) return (unsigned char)(s | 0x7Eu);
    if (af < 0.015625f) {                    // subnormal region (< 2^-6)
        int m = (int)rintf(af * 512.f);      // m in 0..8
        if (m >= 8) return (unsigned char)(s | 0x08u);
        return (unsigned char)(s | (unsigned)m);
    }
    unsigned u = v.u & 0x7FFFFFFFu;
    unsigned t = u + 0x000FFFFFu + ((u >> 20) & 1u);   // RNE at 3-bit mantissa
    int e = (int)(t >> 23) - 127;
    unsigned m3 = (t >> 20) & 7u;
    if (e < -6) {
        int m = (int)rintf(af * 512.f);
        if (m >= 8) return (unsigned char)(s | 0x08u);
        return (unsigned char)(s | (unsigned)m);
    }
    if (e > 8 || (e == 8 && m3 == 7u)) return (unsigned char)(s | 0x7Eu);
    return (unsigned char)(s | (((unsigned)(e + 7)) << 3) | m3);
}

// fp8 e4m3fn decode (hot path): bit-splice into f32, scale by 2^120.
// Exact for normals and subnormals; we never encode NaN.
static __device__ __forceinline__ float fp8tof(unsigned b) {
    union { unsigned u; float f; } v;
    v.u = ((b & 0x80u) << 24) | ((b & 0x7Fu) << 20);
    return v.f * 0x1p120f;
}

// ---------------------------------------------------------------------------
// Prepack B^T bf16: Bt[n][k]; n<256 -> W[:,n] (h), n>=256 -> W_gc[:,n-256] (g)
// ---------------------------------------------------------------------------
__global__ __launch_bounds__(512) void bt_pack(const float* __restrict__ W,
                                               const float* __restrict__ W_gc,
                                               short* __restrict__ Bt) {
    const int n = blockIdx.x;
    const int k = threadIdx.x;
    float v = (n < OUT_F) ? W[(size_t)k * OUT_F + n]
                          : W_gc[(size_t)k * OUT_F + (n - OUT_F)];
    Bt[(size_t)n * IN_F + k] = f2bf(v);
}

// ---------------------------------------------------------------------------
// MFMA bf16 GEMM.  cat-cols <256 = h -> fp8 into hrow[.][0:256] + bf16 hbf;
// cat-cols >=256 = g -> bf16 into hrow[.][256:768].
// ---------------------------------------------------------------------------
__global__ __launch_bounds__(256) void gemm_mfma(const float* __restrict__ A,
                                                 const short* __restrict__ Bt,
                                                 unsigned char* __restrict__ hrow,
                                                 short* __restrict__ hbf) {
    __shared__ short As[128 * 32];
    __shared__ short Bs[128 * 32];

    const int tid  = threadIdx.x;
    const int m0   = blockIdx.y * 128;
    const int n0   = blockIdx.x * 128;
    const int wid  = tid >> 6;
    const int lane = tid & 63;
    const int wr   = wid >> 1;
    const int wc   = wid & 1;
    const int mh   = lane & 15;
    const int q    = lane >> 4;

    const int srow  = tid >> 1;
    const int shalf = tid & 1;

    const f32x4 vzero = {0.f, 0.f, 0.f, 0.f};
    f32x4 acc[4][4];
    #pragma unroll
    for (int i = 0; i < 4; i++)
        #pragma unroll
        for (int j = 0; j < 4; j++) acc[i][j] = vzero;

    const float* aga = A  + (size_t)(m0 + srow) * IN_F + shalf * 16;
    const short* bgb = Bt + (size_t)(n0 + srow) * IN_F + shalf * 16;
    short* asw = &As[srow * 32 + shalf * 16];
    short* bsw = &Bs[srow * 32 + shalf * 16];

    for (int k0 = 0; k0 < IN_F; k0 += 32) {
        const float4* a4 = (const float4*)(aga + k0);
        float4 x0 = a4[0], x1 = a4[1], x2 = a4[2], x3 = a4[3];
        const int4* b4 = (const int4*)(bgb + k0);
        int4 bv0 = b4[0], bv1 = b4[1];

        short8 p0, p1;
        p0[0] = f2bf(x0.x); p0[1] = f2bf(x0.y); p0[2] = f2bf(x0.z); p0[3] = f2bf(x0.w);
        p0[4] = f2bf(x1.x); p0[5] = f2bf(x1.y); p0[6] = f2bf(x1.z); p0[7] = f2bf(x1.w);
        p1[0] = f2bf(x2.x); p1[1] = f2bf(x2.y); p1[2] = f2bf(x2.z); p1[3] = f2bf(x2.w);
        p1[4] = f2bf(x3.x); p1[5] = f2bf(x3.y); p1[6] = f2bf(x3.z); p1[7] = f2bf(x3.w);

        __syncthreads();
        *(short8*)asw       = p0;
        *(short8*)(asw + 8) = p1;
        *(int4*)bsw         = bv0;
        *(int4*)(bsw + 8)   = bv1;
        __syncthreads();

        short8 af[4], bfm[4];
        #pragma unroll
        for (int i = 0; i < 4; i++) {
            af[i]  = *(const short8*)&As[(wr * 64 + i * 16 + mh) * 32 + q * 8];
            bfm[i] = *(const short8*)&Bs[(wc * 64 + i * 16 + mh) * 32 + q * 8];
        }
        #pragma unroll
        for (int mi = 0; mi < 4; mi++)
            #pragma unroll
            for (int ni = 0; ni < 4; ni++)
                acc[mi][ni] = __builtin_amdgcn_mfma_f32_16x16x32_bf16(
                    af[mi], bfm[ni], acc[mi][ni], 0, 0, 0);
    }

    if (n0 < OUT_F) {
        #pragma unroll
        for (int mi = 0; mi < 4; mi++)
            #pragma unroll
            for (int ni = 0; ni < 4; ni++) {
                const int col   = n0 + wc * 64 + ni * 16 + mh;
                const int rbase = m0 + wr * 64 + mi * 16 + q * 4;
                f32x4 v = acc[mi][ni];
                #pragma unroll
                for (int r = 0; r < 4; r++) {
                    float x = v[r];
                    hbf[(size_t)(rbase + r) * OUT_F + col] = f2bf(x);
                    hrow[(size_t)(rbase + r) * RSTRIDE + col] = f2fp8(x);
                }
            }
    } else {
        #pragma unroll
        for (int mi = 0; mi < 4; mi++)
            #pragma unroll
            for (int ni = 0; ni < 4; ni++) {
                const int col   = (n0 - OUT_F) + wc * 64 + ni * 16 + mh;
                const int rbase = m0 + wr * 64 + mi * 16 + q * 4;
                f32x4 v = acc[mi][ni];
                #pragma unroll
                for (int r = 0; r < 4; r++)
                    *(short*)(hrow + (size_t)(rbase + r) * RSTRIDE + 256 + 2 * col)
                        = f2bf(v[r]);
            }
    }
}

// ---------------------------------------------------------------------------
// f_src[i] = h[i,:].a[0:256], f_dst[i] = h[i,:].a[256:512]  (bf16 hbf table)
// ---------------------------------------------------------------------------
__global__ __launch_bounds__(256) void compute_f(const short* __restrict__ hbf,
                                                 const float* __restrict__ a,
                                                 float* __restrict__ f_src,
                                                 float* __restrict__ f_dst) {
    const int row  = blockIdx.x * 4 + (threadIdx.x >> 6);
    const int lane = threadIdx.x & 63;
    const int c0   = lane * 4;
    short4e v = *(const short4e*)(hbf + (size_t)row * OUT_F + c0);
    float s1 = 0.f, s2 = 0.f;
    #pragma unroll
    for (int i = 0; i < 4; i++) {
        float hv = bf2f(v[i]);
        s1 += hv * a[c0 + i];
        s2 += hv * a[OUT_F + c0 + i];
    }
    #pragma unroll
    for (int off = 32; off; off >>= 1) {
        s1 += __shfl_down(s1, off);
        s2 += __shfl_down(s2, off);
    }
    if (lane == 0) { f_src[row] = s1; f_dst[row] = s2; }
}

// ---------------------------------------------------------------------------
// Fused per-row attention + graph-conv (R6 structure, 768 B records).
// Phase 1: register-prefetch full 32 KB adj slice (8 f32x4/thread), compact
//          (idx, w=exp(lrelu(fs+fd))) into LDS.  No max-shift (validated).
// Phase 3: wave wid takes neighbors k=wid (mod 4); ONE wave covers the whole
//          768 B record: lane L loads 4 fp8 h (u32) + 4 bf16 g (8 B) for
//          cols 4L..4L+3.  Cross-wave reduce via 9.2 KB LDS. 13.5 KB total.
// ---------------------------------------------------------------------------
__global__ __launch_bounds__(256) void attn_row(const float* __restrict__ adj,
                                                const unsigned char* __restrict__ hrow,
                                                const float* __restrict__ f_src,
                                                const float* __restrict__ f_dst,
                                                const float* __restrict__ b_gc,
                                                float* __restrict__ out) {
    __shared__ int   s_idx[MAXDEG];
    __shared__ float s_w[MAXDEG];
    __shared__ float s_red[4];
    __shared__ int   s_count;
    __shared__ float s_part[4][64][9];   // [wave][lane][4 h + 4 g], pad 9

    const int row  = blockIdx.x;
    const int tid  = threadIdx.x;
    const int lane = tid & 63;
    const int wid  = tid >> 6;

    if (tid == 0) s_count = 0;
    __syncthreads();

    const float fs = f_src[row];
    const f32x4* arow4 = (const f32x4*)(adj + (size_t)row * N_NODES);

    // Phase 1a: issue all 8 loads back-to-back
    f32x4 v[8];
    #pragma unroll
    for (int it = 0; it < 8; it++)
        v[it] = arow4[it * 256 + tid];

    // Phase 1b: compact hits
    float lloc = 0.f;
    #pragma unroll
    for (int it = 0; it < 8; it++) {
        int c4 = (v[it][0] > 0.f) + (v[it][1] > 0.f) +
                 (v[it][2] > 0.f) + (v[it][3] > 0.f);
        if (c4) {
            int pos = atomicAdd(&s_count, c4);
            const int j0 = (it * 256 + tid) * 4;
            #pragma unroll
            for (int i = 0; i < 4; i++) {
                if (v[it][i] > 0.f) {
                    float e = fs + f_dst[j0 + i];
                    e = (e > 0.f) ? e : ALPHA * e;
                    float w = __expf(e);
                    s_idx[pos] = j0 + i;
                    s_w[pos]   = w;
                    pos++;
                    lloc += w;
                }
            }
        }
    }
    #pragma unroll
    for (int off = 32; off; off >>= 1) lloc += __shfl_down(lloc, off);
    if (lane == 0) s_red[wid] = lloc;
    __syncthreads();

    const int   deg   = min(s_count, MAXDEG);
    const float l     = s_red[0] + s_red[1] + s_red[2] + s_red[3];
    const float inv_l = (deg > 0) ? 1.f / l : 0.f;

    // Phase 3: gather.  lane L -> cols 4L..4L+3.
    const unsigned char* hb = hrow + lane * 4;          // fp8 h, 4 B
    const unsigned char* gb = hrow + 256 + lane * 8;    // bf16 g, 8 B

    float ah[4] = {0.f, 0.f, 0.f, 0.f};
    float ag[4] = {0.f, 0.f, 0.f, 0.f};
    #pragma unroll 4
    for (int k = wid; k < deg; k += 4) {
        const size_t off = (size_t)s_idx[k] * RSTRIDE;
        const float  w   = s_w[k];
        unsigned hp = *(const unsigned*)(hb + off);
        short4e  gp = *(const short4e*)(gb + off);
        ah[0] += w * fp8tof(hp & 0xFFu);
        ah[1] += w * fp8tof((hp >> 8) & 0xFFu);
        ah[2] += w * fp8tof((hp >> 16) & 0xFFu);
        ah[3] += w * fp8tof(hp >> 24);
        #pragma unroll
        for (int i = 0; i < 4; i++) ag[i] += bf2f(gp[i]);
    }
    #pragma unroll
    for (int i = 0; i < 4; i++) {
        s_part[wid][lane][i]     = ah[i];
        s_part[wid][lane][4 + i] = ag[i];
    }
    __syncthreads();

    // Final reduce: thread tid owns output col tid.
    const int pc = tid >> 2, ic = tid & 3;
    float h_tot = s_part[0][pc][ic]     + s_part[1][pc][ic]
                + s_part[2][pc][ic]     + s_part[3][pc][ic];
    float g_tot = s_part[0][pc][4 + ic] + s_part[1][pc][4 + ic]
                + s_part[2][pc][4 + ic] + s_part[3][pc][4 + ic];
    out[(size_t)row * OUT_F + tid] = h_tot * inv_l + g_tot + b_gc[tid];
}

// ---------------------------------------------------------------------------
extern "C" void kernel_launch(void* const* d_in, const int* in_sizes, int n_in,
                              void* d_out, int out_size, void* d_ws, size_t ws_size,
                              hipStream_t stream) {
    const float* inputs = (const float*)d_in[0];   // [8192,512]
    const float* adj    = (const float*)d_in[1];   // [8192,8192]
    const float* W      = (const float*)d_in[2];   // [512,256]
    const float* a      = (const float*)d_in[3];   // [512,1]
    const float* W_gc   = (const float*)d_in[4];   // [512,256]
    const float* b_gc   = (const float*)d_in[5];   // [256]
    float* out = (float*)d_out;                    // [8192,256]

    short*         Bt    = (short*)d_ws;                              // 0.5 MB
    unsigned char* hrow  = (unsigned char*)(Bt + (size_t)NCAT * IN_F);// 6 MB
    short*         hbf   = (short*)(hrow + (size_t)N_NODES * RSTRIDE);// 4 MB
    float*         f_src = (float*)(hbf + (size_t)N_NODES * OUT_F);   // 32 KB
    float*         f_dst = f_src + N_NODES;                           // 32 KB

    bt_pack<<<dim3(NCAT), dim3(IN_F), 0, stream>>>(W, W_gc, Bt);
    gemm_mfma<<<dim3(NCAT / 128, N_NODES / 128), 256, 0, stream>>>(inputs, Bt, hrow, hbf);
    compute_f<<<N_NODES / 4, 256, 0, stream>>>(hbf, a, f_src, f_dst);
    attn_row<<<N_NODES, 256, 0, stream>>>(adj, hrow, f_src, f_dst, b_gc, out);
}

// Round 9
// 424.689 us; speedup vs baseline: 1.0552x; 1.0239x over previous
//
#include <hip/hip_runtime.h>
#include <hip/hip_bf16.h>
#include <math.h>

#define N_NODES 8192
#define IN_F    512
#define OUT_F   256
#define NCAT    512          // interleaved (h,hgc) columns
#define ALPHA   0.2f
#define MAXDEG  512          // Binomial(8192,1/128): mean 64, sd 8 -> 512 unreachable

typedef __attribute__((ext_vector_type(8))) short short8;
typedef __attribute__((ext_vector_type(4))) float f32x4;

static __device__ __forceinline__ short f2bf(float f) {
    union { float f; unsigned u; } v; v.f = f;
    unsigned r = v.u + 0x7fffu + ((v.u >> 16) & 1u);   // RNE
    return (short)(r >> 16);
}
static __device__ __forceinline__ float bf2f(short s) {
    union { unsigned u; float f; } v;
    v.u = ((unsigned)(unsigned short)s) << 16;
    return v.f;
}

// ---------------------------------------------------------------------------
// Prepack B^T bf16, interleaved: Bt[n][k], n=2c -> W[:,c], n=2c+1 -> W_gc[:,c]
// ---------------------------------------------------------------------------
__global__ __launch_bounds__(512) void bt_pack(const float* __restrict__ W,
                                               const float* __restrict__ W_gc,
                                               short* __restrict__ Bt) {
    const int n = blockIdx.x;    // 0..511
    const int k = threadIdx.x;   // 0..511
    const int c = n >> 1;
    float v = (n & 1) ? W_gc[(size_t)k * OUT_F + c] : W[(size_t)k * OUT_F + c];
    Bt[(size_t)n * IN_F + k] = f2bf(v);
}

// ---------------------------------------------------------------------------
// MFMA bf16 GEMM: hcat[8192][512](bf16) = bf16(inputs[8192][512]) @ Bt^T
// 128x128 tile / block, 4 waves 2x2, each wave 4x4 of 16x16x32 MFMAs.
// ---------------------------------------------------------------------------
__global__ __launch_bounds__(256) void gemm_mfma(const float* __restrict__ A,
                                                 const short* __restrict__ Bt,
                                                 short* __restrict__ hcat) {
    __shared__ short As[128 * 32];   // [row][k] k-contiguous
    __shared__ short Bs[128 * 32];   // [col][k]

    const int tid  = threadIdx.x;
    const int m0   = blockIdx.y * 128;
    const int n0   = blockIdx.x * 128;
    const int wid  = tid >> 6;
    const int lane = tid & 63;
    const int wr   = wid >> 1;
    const int wc   = wid & 1;
    const int mh   = lane & 15;
    const int q    = lane >> 4;

    const int srow  = tid >> 1;
    const int shalf = tid & 1;

    const f32x4 vzero = {0.f, 0.f, 0.f, 0.f};
    f32x4 acc[4][4];
    #pragma unroll
    for (int i = 0; i < 4; i++)
        #pragma unroll
        for (int j = 0; j < 4; j++) acc[i][j] = vzero;

    const float* aga = A  + (size_t)(m0 + srow) * IN_F + shalf * 16;
    const short* bgb = Bt + (size_t)(n0 + srow) * IN_F + shalf * 16;
    short* asw = &As[srow * 32 + shalf * 16];
    short* bsw = &Bs[srow * 32 + shalf * 16];

    for (int k0 = 0; k0 < IN_F; k0 += 32) {
        const float4* a4 = (const float4*)(aga + k0);
        float4 x0 = a4[0], x1 = a4[1], x2 = a4[2], x3 = a4[3];
        const int4* b4 = (const int4*)(bgb + k0);
        int4 bv0 = b4[0], bv1 = b4[1];

        short8 p0, p1;
        p0[0] = f2bf(x0.x); p0[1] = f2bf(x0.y); p0[2] = f2bf(x0.z); p0[3] = f2bf(x0.w);
        p0[4] = f2bf(x1.x); p0[5] = f2bf(x1.y); p0[6] = f2bf(x1.z); p0[7] = f2bf(x1.w);
        p1[0] = f2bf(x2.x); p1[1] = f2bf(x2.y); p1[2] = f2bf(x2.z); p1[3] = f2bf(x2.w);
        p1[4] = f2bf(x3.x); p1[5] = f2bf(x3.y); p1[6] = f2bf(x3.z); p1[7] = f2bf(x3.w);

        __syncthreads();
        *(short8*)asw       = p0;
        *(short8*)(asw + 8) = p1;
        *(int4*)bsw         = bv0;
        *(int4*)(bsw + 8)   = bv1;
        __syncthreads();

        short8 af[4], bfm[4];
        #pragma unroll
        for (int i = 0; i < 4; i++) {
            af[i]  = *(const short8*)&As[(wr * 64 + i * 16 + mh) * 32 + q * 8];
            bfm[i] = *(const short8*)&Bs[(wc * 64 + i * 16 + mh) * 32 + q * 8];
        }
        #pragma unroll
        for (int mi = 0; mi < 4; mi++)
            #pragma unroll
            for (int ni = 0; ni < 4; ni++)
                acc[mi][ni] = __builtin_amdgcn_mfma_f32_16x16x32_bf16(
                    af[mi], bfm[ni], acc[mi][ni], 0, 0, 0);
    }

    #pragma unroll
    for (int mi = 0; mi < 4; mi++)
        #pragma unroll
        for (int ni = 0; ni < 4; ni++) {
            const int col   = n0 + wc * 64 + ni * 16 + mh;
            const int rbase = m0 + wr * 64 + mi * 16 + q * 4;
            f32x4 v = acc[mi][ni];
            #pragma unroll
            for (int r = 0; r < 4; r++)
                hcat[(size_t)(rbase + r) * NCAT + col] = f2bf(v[r]);
        }
}

// ---------------------------------------------------------------------------
// f_src[i] = h[i,:].a[0:256], f_dst[i] = h[i,:].a[256:512]; h = hcat[:, even]
// ---------------------------------------------------------------------------
__global__ __launch_bounds__(256) void compute_f(const short* __restrict__ hcat,
                                                 const float* __restrict__ a,
                                                 float* __restrict__ f_src,
                                                 float* __restrict__ f_dst) {
    const int row  = blockIdx.x * 4 + (threadIdx.x >> 6);
    const int lane = threadIdx.x & 63;
    const short* hr = hcat + (size_t)row * NCAT;
    float s1 = 0.f, s2 = 0.f;
    #pragma unroll
    for (int c = lane; c < OUT_F; c += 64) {
        float hv = bf2f(hr[2 * c]);
        s1 += hv * a[c];
        s2 += hv * a[OUT_F + c];
    }
    #pragma unroll
    for (int off = 32; off; off >>= 1) {
        s1 += __shfl_down(s1, off);
        s2 += __shfl_down(s2, off);
    }
    if (lane == 0) { f_src[row] = s1; f_dst[row] = s2; }
}

// ---------------------------------------------------------------------------
// Fused per-row attention + graph-conv.  LDS = 4.2 KB.
// Phase 1: register-prefetch the entire 32 KB adj row slice (8 independent
//          f32x4 loads/thread, one wait), then compact (idx, w=exp(lrelu))
//          into LDS.  No max-subtraction (|fs+fd| <~ 20, fp32-safe).
// Phase 2: block sum of w.
// Phase 3: wave w owns cols [64w,64w+64); lane = 16u+p handles neighbors
//          k=u (mod 4) for cols 4p..4p+3 via one short8 load of the
//          interleaved hcat row; reduce over u via 2 shuffles; u==0
//          lanes write float4.
// ---------------------------------------------------------------------------
__global__ __launch_bounds__(256) void attn_row(const float* __restrict__ adj,
                                                const short* __restrict__ hcat,
                                                const float* __restrict__ f_src,
                                                const float* __restrict__ f_dst,
                                                const float* __restrict__ b_gc,
                                                float* __restrict__ out) {
    __shared__ int   s_idx[MAXDEG];
    __shared__ float s_w[MAXDEG];
    __shared__ float s_red[4];
    __shared__ int   s_count;

    const int row  = blockIdx.x;
    const int tid  = threadIdx.x;
    const int lane = tid & 63;
    const int wid  = tid >> 6;

    if (tid == 0) s_count = 0;
    __syncthreads();

    const float fs = f_src[row];
    const f32x4* arow4 = (const f32x4*)(adj + (size_t)row * N_NODES);

    // ---- Phase 1a: issue all 8 loads, no consumption in between ----
    f32x4 v[8];
    #pragma unroll
    for (int it = 0; it < 8; it++)
        v[it] = arow4[it * 256 + tid];

    // ---- Phase 1b: compact hits into LDS ----
    float lloc = 0.f;
    #pragma unroll
    for (int it = 0; it < 8; it++) {
        int c4 = (v[it][0] > 0.f) + (v[it][1] > 0.f) +
                 (v[it][2] > 0.f) + (v[it][3] > 0.f);
        if (c4) {
            int pos = atomicAdd(&s_count, c4);
            const int j0 = (it * 256 + tid) * 4;
            #pragma unroll
            for (int i = 0; i < 4; i++) {
                if (v[it][i] > 0.f) {
                    float e = fs + f_dst[j0 + i];
                    e = (e > 0.f) ? e : ALPHA * e;
                    float w = __expf(e);          // no max-shift needed
                    s_idx[pos] = j0 + i;
                    s_w[pos]   = w;
                    pos++;
                    lloc += w;
                }
            }
        }
    }
    #pragma unroll
    for (int off = 32; off; off >>= 1) lloc += __shfl_down(lloc, off);
    if (lane == 0) s_red[wid] = lloc;
    __syncthreads();                              // list + sums visible

    const int   deg   = min(s_count, MAXDEG);
    const float l     = s_red[0] + s_red[1] + s_red[2] + s_red[3];
    const float inv_l = (deg > 0) ? 1.f / l : 0.f;

    // ---- Phase 3: gather ----
    const int u = lane >> 4;         // neighbor subgroup 0..3
    const int p = lane & 15;         // column group: cols 64*wid + 4p..4p+3
    const short* hbase = hcat + wid * 128 + p * 8;

    float aa0 = 0.f, aa1 = 0.f, aa2 = 0.f, aa3 = 0.f;
    float gg0 = 0.f, gg1 = 0.f, gg2 = 0.f, gg3 = 0.f;
    #pragma unroll 4
    for (int k = u; k < deg; k += 4) {
        const int   j = s_idx[k];
        const float w = s_w[k];
        short8 hv = *(const short8*)(hbase + (size_t)j * NCAT);
        aa0 += w * bf2f(hv[0]); gg0 += bf2f(hv[1]);
        aa1 += w * bf2f(hv[2]); gg1 += bf2f(hv[3]);
        aa2 += w * bf2f(hv[4]); gg2 += bf2f(hv[5]);
        aa3 += w * bf2f(hv[6]); gg3 += bf2f(hv[7]);
    }
    // reduce across u (lanes +32 then +16)
    aa0 += __shfl_down(aa0, 32); aa1 += __shfl_down(aa1, 32);
    aa2 += __shfl_down(aa2, 32); aa3 += __shfl_down(aa3, 32);
    gg0 += __shfl_down(gg0, 32); gg1 += __shfl_down(gg1, 32);
    gg2 += __shfl_down(gg2, 32); gg3 += __shfl_down(gg3, 32);
    aa0 += __shfl_down(aa0, 16); aa1 += __shfl_down(aa1, 16);
    aa2 += __shfl_down(aa2, 16); aa3 += __shfl_down(aa3, 16);
    gg0 += __shfl_down(gg0, 16); gg1 += __shfl_down(gg1, 16);
    gg2 += __shfl_down(gg2, 16); gg3 += __shfl_down(gg3, 16);

    if (u == 0) {
        const int col = wid * 64 + p * 4;
        const float4 bg = *(const float4*)(b_gc + col);
        float4 o;
        o.x = aa0 * inv_l + gg0 + bg.x;
        o.y = aa1 * inv_l + gg1 + bg.y;
        o.z = aa2 * inv_l + gg2 + bg.z;
        o.w = aa3 * inv_l + gg3 + bg.w;
        *(float4*)(out + (size_t)row * OUT_F + col) = o;
    }
}

// ---------------------------------------------------------------------------
extern "C" void kernel_launch(void* const* d_in, const int* in_sizes, int n_in,
                              void* d_out, int out_size, void* d_ws, size_t ws_size,
                              hipStream_t stream) {
    const float* inputs = (const float*)d_in[0];   // [8192,512]
    const float* adj    = (const float*)d_in[1];   // [8192,8192]
    const float* W      = (const float*)d_in[2];   // [512,256]
    const float* a      = (const float*)d_in[3];   // [512,1]
    const float* W_gc   = (const float*)d_in[4];   // [512,256]
    const float* b_gc   = (const float*)d_in[5];   // [256]
    float* out = (float*)d_out;                    // [8192,256]

    short* Bt    = (short*)d_ws;                            // 512*512 bf16
    short* hcat  = Bt + (size_t)NCAT * IN_F;                // 8192*512 bf16
    float* f_src = (float*)(hcat + (size_t)N_NODES * NCAT); // 8192
    float* f_dst = f_src + N_NODES;                         // 8192

    bt_pack<<<dim3(NCAT), dim3(IN_F), 0, stream>>>(W, W_gc, Bt);
    gemm_mfma<<<dim3(NCAT / 128, N_NODES / 128), 256, 0, stream>>>(inputs, Bt, hcat);
    compute_f<<<N_NODES / 4, 256, 0, stream>>>(hcat, a, f_src, f_dst);
    attn_row<<<N_NODES, 256, 0, stream>>>(adj, hcat, f_src, f_dst, b_gc, out);
}